// Round 1
// 1779.696 us; speedup vs baseline: 1.0890x; 1.0890x over previous
//
#include <hip/hip_runtime.h>
#include <hip/hip_bf16.h>
#include <cstdio>

typedef unsigned short ushort_t;
typedef __bf16 bf16x8 __attribute__((ext_vector_type(8)));
typedef float f32x4 __attribute__((ext_vector_type(4)));

#define FL   160000      // final sequence length
#define L0   165110      // causal conv output length
#define NL   45
#define CH   80000       // time-chunk for the GEMM chain

__device__ __forceinline__ float tanh_fast(float x) {
    float ax = fabsf(x);
    float e  = __expf(-2.f * ax);
    float r  = (1.f - e) / (1.f + e);
    return copysignf(r, x);
}
__device__ __forceinline__ float sigmoid_fast(float x) {
    return 1.f / (1.f + __expf(-x));
}

#define GLOAD_LDS16(gp, lp) \
    __builtin_amdgcn_global_load_lds( \
        (const __attribute__((address_space(1))) void*)(gp), \
        (__attribute__((address_space(3))) void*)(lp), 16, 0, 0)

// ---------------------------------------------------------------------------
// Causal conv: y[t][oc] = b[oc] + sum_k w[oc][k] * x[t+k],  t < L0
// Output layout: fp32 [t][32] rows.
// ---------------------------------------------------------------------------
__global__ __launch_bounds__(256) void causal_kernel(
    const float* __restrict__ x, const float* __restrict__ wc,
    const float* __restrict__ bc, float* __restrict__ y)
{
    __shared__ float ws_[33 * 32];
    __shared__ float bs_[32];
    const int tid = threadIdx.x;
    for (int idx = tid; idx < 33 * 32; idx += 256) {
        int k = idx >> 5, oc = idx & 31;
        ws_[idx] = wc[oc * 33 + k];             // [k][oc]
    }
    if (tid < 32) bs_[tid] = bc[tid];
    __syncthreads();
    const int t = blockIdx.x * 256 + tid;
    if (t >= L0) return;
    float acc[32];
#pragma unroll
    for (int oc = 0; oc < 32; ++oc) acc[oc] = bs_[oc];
    for (int k = 0; k < 33; ++k) {
        float xv = x[t + k];
        const float* wp = &ws_[k * 32];
#pragma unroll
        for (int oc = 0; oc < 32; ++oc) acc[oc] += wp[oc] * xv;
    }
    float* yr = y + (size_t)t * 32;
#pragma unroll
    for (int oc = 0; oc < 32; oc += 4)
        *(float4*)(yr + oc) = make_float4(acc[oc], acc[oc+1], acc[oc+2], acc[oc+3]);
}

// ---------------------------------------------------------------------------
// Prepack conv (tanh+sig stacked, M=64, K=96=(tap,ic)) and dense (M=32,K=32)
// weights into MFMA A-fragment layout: frag[slot][lane][8],
// A[m = slot_m*16 + (lane&15)][k = (lane>>4)*8 + jj].
// ---------------------------------------------------------------------------
__global__ __launch_bounds__(256) void prepack_frag(
    const float* __restrict__ wt, const float* __restrict__ wsg,
    const float* __restrict__ wd,
    __bf16* __restrict__ fragConv, __bf16* __restrict__ fragDense)
{
    const int idx = blockIdx.x * 256 + threadIdx.x;
    if (idx < NL * 12 * 64) {
        const int lane = idx & 63;
        const int rem  = idx >> 6;
        const int slot = rem % 12, l = rem / 12;
        const int j = slot >> 2, i = slot & 3;        // tap, m-tile
        const int m = (i & 1) * 16 + (lane & 15);     // row within 32
        const int quad = lane >> 4;
        const float* wsrc = (i < 2) ? wt : wsg;
        __bf16 v[8];
#pragma unroll
        for (int jj = 0; jj < 8; ++jj) {
            int ic = quad * 8 + jj;
            v[jj] = (__bf16)wsrc[((size_t)(l * 32 + m) * 32 + ic) * 3 + j];
        }
        *(uint4*)(fragConv + (size_t)idx * 8) = *(const uint4*)v;
    }
    if (idx < NL * 2 * 64) {
        const int lane = idx & 63;
        const int rem  = idx >> 6;
        const int i = rem & 1, l = rem >> 1;
        const int m = i * 16 + (lane & 15);
        const int quad = lane >> 4;
        __bf16 v[8];
#pragma unroll
        for (int jj = 0; jj < 8; ++jj)
            v[jj] = (__bf16)wd[(size_t)(l * 32 + m) * 32 + quad * 8 + jj];
        *(uint4*)(fragDense + (size_t)idx * 8) = *(const uint4*)v;
    }
}

// ---------------------------------------------------------------------------
// Fully-fused MFMA layer: conv(tanh|sig) -> gate -> skip slab (bf16) +
// dense + residual (fp32). x layout [t][32] fp32. Wave-private LDS slab,
// no __syncthreads. Each wave owns 32 t's; block = 128 t's.
// ---------------------------------------------------------------------------
__global__ __launch_bounds__(256) void layer_mfma(
    const float* __restrict__ xin,   // [Lin][32] fp32, Lin = Lout + 2d
    float* __restrict__ xout,        // [Lout][32] fp32
    __bf16* __restrict__ xslot,      // XcatT + l*32, row stride 1440
    const __bf16* __restrict__ fragConv,   // layer's 12*64*8
    const __bf16* __restrict__ fragDense,  // layer's 2*64*8
    const float* __restrict__ bt, const float* __restrict__ bs,
    const float* __restrict__ bd,
    int d, int Lout, int S)
{
    __shared__ __bf16 gbuf[4][32][40];   // per-wave slab, ic padded 32->40
    const int tid  = threadIdx.x;
    const int wave = tid >> 6, lane = tid & 63;
    const int fm = lane & 15, quad = lane >> 4;
    const int t0 = blockIdx.x * 128 + wave * 32;

    // A fragments (uniform across waves, L1-hot)
    bf16x8 Ac[3][4], Ad[2];
#pragma unroll
    for (int j = 0; j < 3; ++j)
#pragma unroll
        for (int i = 0; i < 4; ++i)
            Ac[j][i] = *(const bf16x8*)(fragConv + ((j * 4 + i) * 64 + lane) * 8);
#pragma unroll
    for (int i = 0; i < 2; ++i)
        Ad[i] = *(const bf16x8*)(fragDense + (i * 64 + lane) * 8);

    // conv accumulators init with biases: m-tiles 0,1 = tanh rows, 2,3 = sig
    f32x4 acc[4][2];
#pragma unroll
    for (int i = 0; i < 4; ++i) {
        const float* bb = (i < 2) ? (bt + i * 16) : (bs + (i - 2) * 16);
        float4 b4 = *(const float4*)(bb + quad * 4);
        f32x4 bi; bi[0] = b4.x; bi[1] = b4.y; bi[2] = b4.z; bi[3] = b4.w;
        acc[i][0] = bi; acc[i][1] = bi;
    }

    // conv MFMAs: B built on the fly from fp32 x rows
#pragma unroll
    for (int j2 = 0; j2 < 2; ++j2) {
        int tl = t0 + j2 * 16 + fm;
        if (tl > Lout - 1) tl = Lout - 1;
#pragma unroll
        for (int j = 0; j < 3; ++j) {
            const float* xp = xin + (size_t)(tl + j * d) * 32 + quad * 8;
            float4 u0 = *(const float4*)xp;
            float4 u1 = *(const float4*)(xp + 4);
            bf16x8 bf;
            bf[0] = (__bf16)u0.x; bf[1] = (__bf16)u0.y;
            bf[2] = (__bf16)u0.z; bf[3] = (__bf16)u0.w;
            bf[4] = (__bf16)u1.x; bf[5] = (__bf16)u1.y;
            bf[6] = (__bf16)u1.z; bf[7] = (__bf16)u1.w;
#pragma unroll
            for (int i = 0; i < 4; ++i)
                acc[i][j2] = __builtin_amdgcn_mfma_f32_16x16x32_bf16(
                    Ac[j][i], bf, acc[i][j2], 0, 0, 0);
        }
    }

    // gate: g[ic][t] = tanh(z_t) * sigmoid(z_s); write to wave slab [t][ic]
#pragma unroll
    for (int i = 0; i < 2; ++i)
#pragma unroll
        for (int j2 = 0; j2 < 2; ++j2) {
            __bf16 pk[4];
#pragma unroll
            for (int r = 0; r < 4; ++r)
                pk[r] = (__bf16)(tanh_fast(acc[i][j2][r]) *
                                 sigmoid_fast(acc[i + 2][j2][r]));
            *(uint2*)&gbuf[wave][j2 * 16 + fm][i * 16 + quad * 4] =
                *(const uint2*)pk;
        }

    // skip slab: 64 B per t row -> XcatT[tw][l*32 .. +32), 32 B per lane
    {
        const int rr = lane >> 1, hh = lane & 1;
        const int t = t0 + rr, tw = t - S;
        if (t < Lout && (unsigned)tw < FL) {
            const char* gp = (const char*)&gbuf[wave][rr][0] + hh * 32;
            uint4 v0 = *(const uint4*)gp;
            uint4 v1 = *(const uint4*)(gp + 16);
            uint4* dst = (uint4*)(xslot + (size_t)tw * 1440 + hh * 16);
            dst[0] = v0; dst[1] = v1;
        }
    }

    // dense MFMA from slab + residual + fp32 store
    f32x4 dacc[2][2];
#pragma unroll
    for (int i = 0; i < 2; ++i) {
        float4 b4 = *(const float4*)(bd + i * 16 + quad * 4);
        f32x4 bi; bi[0] = b4.x; bi[1] = b4.y; bi[2] = b4.z; bi[3] = b4.w;
        dacc[i][0] = bi; dacc[i][1] = bi;
    }
#pragma unroll
    for (int j2 = 0; j2 < 2; ++j2) {
        bf16x8 gb = *(const bf16x8*)&gbuf[wave][j2 * 16 + fm][quad * 8];
#pragma unroll
        for (int i = 0; i < 2; ++i)
            dacc[i][j2] = __builtin_amdgcn_mfma_f32_16x16x32_bf16(
                Ad[i], gb, dacc[i][j2], 0, 0, 0);
    }
#pragma unroll
    for (int i = 0; i < 2; ++i)
#pragma unroll
        for (int j2 = 0; j2 < 2; ++j2) {
            const int t = t0 + j2 * 16 + fm;
            if (t < Lout) {
                const int oc = i * 16 + quad * 4;
                float4 r4 = *(const float4*)(xin + (size_t)(t + d) * 32 + oc);
                float4 o;
                o.x = dacc[i][j2][0] + r4.x;
                o.y = dacc[i][j2][1] + r4.y;
                o.z = dacc[i][j2][2] + r4.z;
                o.w = dacc[i][j2][3] + r4.w;
                *(float4*)(xout + (size_t)t * 32 + oc) = o;
            }
        }
}

// ---------------------------------------------------------------------------
// Deep-pipelined MFMA bf16 GEMM: C(MxN) = A(MxK) @ Bt(NxK)^T + bias.
//   BM=256 (M/256 blocks), BN=256 (clamped vs Ncur), BK=32 (K % 32 == 0).
//   8 waves (512 thr), wave tile 128x64 -> acc[8][4] f32x4.
//   4-deep LDS ring (4 x 32KB = 128KB), staged 3 tiles ahead with
//   global_load_lds(16B); gate = s_waitcnt vmcnt(8) + raw s_barrier once per
//   K-tile (tiles t+1,t+2 stay in flight).  Epilogue drains 8 -> 4 -> 0.
//   LDS stays linear for the DMA; bank swizzle (chunk ^= (row>>1)&3, 16B
//   granularity -> exactly 2-way = free) is applied identically to the
//   per-lane GLOBAL source address and the ds_read address (involution).
//   Grid: 1-D nTile*mTile blocks; XCD-bijective swizzle (m204), m-fastest so
//   both m-blocks of one B panel share an XCD's L2 back-to-back.
// ---------------------------------------------------------------------------
template<bool TSTORE>
__global__ __launch_bounds__(512, 2) void gemm256(
    const __bf16* __restrict__ A, int lda,
    const __bf16* __restrict__ Bt, int ldb,
    void* __restrict__ Cout, int ldc,
    const float* __restrict__ bias, int K, int Ncur, int mTile)
{
    __shared__ __bf16 lds[4 * 16384];     // ring: per buf A 8192 el + B 8192 el
    const int tid  = threadIdx.x;
    const int wave = tid >> 6, lane = tid & 63;
    const int fm = lane & 15, quad = lane >> 4;
    const int wm = wave >> 2, wn = wave & 3;     // 2 x 4 wave grid

    // XCD-bijective swizzle, then m-fastest pairing
    const int nwg = gridDim.x;
    const int q8 = nwg >> 3, r8 = nwg & 7;
    const int xcd = blockIdx.x & 7, loc = blockIdx.x >> 3;
    const int sbid = (xcd < r8 ? xcd * (q8 + 1)
                               : r8 * (q8 + 1) + (xcd - r8) * q8) + loc;
    const int m0 = (sbid % mTile) * 256;
    const int n0 = (sbid / mTile) * 256;

    // ---- staging source pointers (per-lane, swizzle-compensated) ----------
    const __bf16* pS[4];
    int dstE[4];
#pragma unroll
    for (int i = 0; i < 4; ++i) {
        const int cidx = (i & 1) * 512 + tid;      // 16B-chunk index in tile
        const int r = cidx >> 2, c = cidx & 3;
        const int cs = c ^ ((r >> 1) & 3);         // inverse == forward swizzle
        if (i < 2) {
            pS[i] = A + (size_t)(m0 + r) * lda + cs * 8;
        } else {
            int rg = n0 + r; if (rg > Ncur - 1) rg = Ncur - 1;
            pS[i] = Bt + (size_t)rg * ldb + cs * 8;
        }
        dstE[i] = ((i < 2) ? 0 : 8192) + (i & 1) * 4096 + wave * 512;
    }

    // ---- ds_read offsets (swizzled; s=(fm>>1)&3 invariant across frags) ---
    const int swz = ((quad ^ ((fm >> 1) & 3)) << 3);
    const int aoff = (wm * 128 + fm) * 32 + swz;
    const int boff = 8192 + (wn * 64 + fm) * 32 + swz;

    f32x4 acc[8][4] = {};

    auto do_stage = [&](int t) {
        const int pb = (t & 3) * 16384;
        const int ko = t * 32;
#pragma unroll
        for (int i = 0; i < 4; ++i)
            GLOAD_LDS16(pS[i] + ko, lds + pb + dstE[i]);
    };
    auto tile_compute = [&](int t) {
        const int pb = (t & 3) * 16384;
        bf16x8 af[8], bg[4];
#pragma unroll
        for (int i = 0; i < 8; ++i)
            af[i] = *(const bf16x8*)(lds + pb + aoff + i * 512);
#pragma unroll
        for (int j = 0; j < 4; ++j)
            bg[j] = *(const bf16x8*)(lds + pb + boff + j * 512);
        __builtin_amdgcn_s_setprio(1);
#pragma unroll
        for (int i = 0; i < 8; ++i)
#pragma unroll
            for (int j = 0; j < 4; ++j)
                acc[i][j] = __builtin_amdgcn_mfma_f32_16x16x32_bf16(
                    af[i], bg[j], acc[i][j], 0, 0, 0);
        __builtin_amdgcn_s_setprio(0);
    };

    const int NT = K >> 5;                 // K-tiles of 32 (>= 4 always here)
    do_stage(0); do_stage(1); do_stage(2);
    for (int t = 0; t < NT - 3; ++t) {
        asm volatile("s_waitcnt vmcnt(8)" ::: "memory");
        __builtin_amdgcn_s_barrier();
        __builtin_amdgcn_sched_barrier(0);
        do_stage(t + 3);
        tile_compute(t);
    }
    asm volatile("s_waitcnt vmcnt(8)" ::: "memory");
    __builtin_amdgcn_s_barrier();
    __builtin_amdgcn_sched_barrier(0);
    tile_compute(NT - 3);
    asm volatile("s_waitcnt vmcnt(4)" ::: "memory");
    __builtin_amdgcn_s_barrier();
    __builtin_amdgcn_sched_barrier(0);
    tile_compute(NT - 2);
    asm volatile("s_waitcnt vmcnt(0)" ::: "memory");
    __builtin_amdgcn_s_barrier();
    __builtin_amdgcn_sched_barrier(0);
    tile_compute(NT - 1);

    // ---- epilogue ---------------------------------------------------------
    if (TSTORE) {
        __bf16* O = (__bf16*)Cout;
#pragma unroll
        for (int i = 0; i < 8; ++i) {
            const int m = m0 + wm * 128 + i * 16 + quad * 4;
            const float4 bv = *(const float4*)(bias + m);
#pragma unroll
            for (int j = 0; j < 4; ++j) {
                const int n = n0 + wn * 64 + j * 16 + fm;
                if (n < Ncur) {
                    __bf16 pk[4];
                    pk[0] = (__bf16)fmaxf(acc[i][j][0] + bv.x, 0.f);
                    pk[1] = (__bf16)fmaxf(acc[i][j][1] + bv.y, 0.f);
                    pk[2] = (__bf16)fmaxf(acc[i][j][2] + bv.z, 0.f);
                    pk[3] = (__bf16)fmaxf(acc[i][j][3] + bv.w, 0.f);
                    *(uint2*)(O + (size_t)n * ldc + m) = *(const uint2*)pk;
                }
            }
        }
    } else {
        float* O = (float*)Cout;
#pragma unroll
        for (int i = 0; i < 8; ++i) {
            const int m = m0 + wm * 128 + i * 16 + quad * 4;
            const float4 bv = *(const float4*)(bias + m);
#pragma unroll
            for (int j = 0; j < 4; ++j) {
                const int n = n0 + wn * 64 + j * 16 + fm;
                if (n < Ncur) {
                    O[(size_t)(m + 0) * ldc + n] = acc[i][j][0] + bv.x;
                    O[(size_t)(m + 1) * ldc + n] = acc[i][j][1] + bv.y;
                    O[(size_t)(m + 2) * ldc + n] = acc[i][j][2] + bv.z;
                    O[(size_t)(m + 3) * ldc + n] = acc[i][j][3] + bv.w;
                }
            }
        }
    }
}

// ---------------------------------------------------------------------------
// Repack skip weights to [oc][l*32+ic] bf16 and sum skip biases over layers.
// ---------------------------------------------------------------------------
__global__ __launch_bounds__(256) void repack_kernel(
    const float* __restrict__ wskip, const float* __restrict__ bskip,
    __bf16* __restrict__ wcat, float* __restrict__ bsum)
{
    const int idx = blockIdx.x * 256 + threadIdx.x;
    if (idx < 512 * 1440) {
        int oc = idx / 1440, lic = idx % 1440;
        int l = lic >> 5, ic = lic & 31;
        wcat[idx] = (__bf16)wskip[((size_t)l * 512 + oc) * 32 + ic];
    }
    if (idx < 512) {
        float s = 0.f;
        for (int l = 0; l < NL; ++l) s += bskip[l * 512 + idx];
        bsum[idx] = s;
    }
}

__global__ __launch_bounds__(256) void repack_post(
    const float* __restrict__ w1, const float* __restrict__ w2,
    __bf16* __restrict__ wp1, __bf16* __restrict__ wp2)
{
    const int idx = blockIdx.x * 256 + threadIdx.x;
    if (idx < 512 * 512) wp1[idx] = (__bf16)w1[idx];
    if (idx < 256 * 512) wp2[idx] = (__bf16)w2[idx];
}

extern "C" void kernel_launch(void* const* d_in, const int* in_sizes, int n_in,
                              void* d_out, int out_size, void* d_ws, size_t ws_size,
                              hipStream_t stream)
{
    const float* x        = (const float*)d_in[0];
    const float* w_causal = (const float*)d_in[1];
    const float* b_causal = (const float*)d_in[2];
    const float* w_tanh   = (const float*)d_in[3];
    const float* b_tanh   = (const float*)d_in[4];
    const float* w_sig    = (const float*)d_in[5];
    const float* b_sig    = (const float*)d_in[6];
    const float* w_skip   = (const float*)d_in[7];
    const float* b_skip   = (const float*)d_in[8];
    const float* w_dense  = (const float*)d_in[9];
    const float* b_dense  = (const float*)d_in[10];
    const float* w_post1  = (const float*)d_in[11];
    const float* b_post1  = (const float*)d_in[12];
    const float* w_post2  = (const float*)d_in[13];
    const float* b_post2  = (const float*)d_in[14];
    float* out = (float*)d_out;

    // Workspace carve (bytes). Budget: ws_size = 655,360,000.
    //   XcatT    bf16 [FL][1440]: 460,800,000  [0 .. 460,800,000)
    //   skipTc   bf16 [CH][512] :  81,920,000  [460,800,000 .. 542,720,000)
    //   hTc      bf16 [CH][512] :  81,920,000  [542,720,000 .. 624,640,000)
    //   wcat     bf16 512x1440  :   1,474,560  [624,640,000 .. 626,114,560)
    //   wp1      bf16 512x512   :     524,288  [626,114,560 .. 626,638,848)
    //   wp2      bf16 256x512   :     262,144  [626,638,848 .. 626,900,992)
    //   bsum     fp32 512       :       2,048  [626,900,992 .. 626,903,040)
    //   fragConv bf16 45*12*512 :     552,960  [626,903,040 .. 627,456,000)
    //   fragDense bf16 45*2*512 :      92,160  [627,456,000 .. 627,548,160)
    //   xb0/xb1 (fp32 [L0][32], 21,135,360 each) overlay skipTc (dead at GEMM time)
    char* base = (char*)d_ws;
    __bf16* XcatT  = (__bf16*)base;
    __bf16* skipTc = (__bf16*)(base + 460800000);
    __bf16* hTc    = (__bf16*)(base + 542720000);
    __bf16* wcat   = (__bf16*)(base + 624640000);
    __bf16* wp1    = (__bf16*)(base + 626114560);
    __bf16* wp2    = (__bf16*)(base + 626638848);
    float*  bsum   = (float*)(base + 626900992);
    __bf16* fragConv  = (__bf16*)(base + 626903040);
    __bf16* fragDense = (__bf16*)(base + 627456000);
    float*  xb0    = (float*)(base + 460800000);
    float*  xb1    = (float*)(base + 460800000 + 21135360);
    const size_t need = 627548160;
    if (ws_size < need) {
        fprintf(stderr, "kernel_launch: ws_size %zu < needed %zu\n", ws_size, need);
        return;
    }

    repack_kernel<<<2880, 256, 0, stream>>>(w_skip, b_skip, wcat, bsum);
    repack_post<<<1024, 256, 0, stream>>>(w_post1, w_post2, wp1, wp2);
    prepack_frag<<<(NL * 12 * 64 + 255) / 256, 256, 0, stream>>>(
        w_tanh, w_sig, w_dense, fragConv, fragDense);
    causal_kernel<<<(L0 + 255) / 256, 256, 0, stream>>>(x, w_causal, b_causal, xb0);

    int Lin = L0;
    int S   = 2555;              // sum of all dilations
    float* xc = xb0;
    float* xn = xb1;
    for (int l = 0; l < NL; ++l) {
        const int d = 1 << (l % 9);
        const int Lout = Lin - 2 * d;
        S -= d;                  // S_l = skip-window start after layer l
        layer_mfma<<<(Lout + 127) / 128, 256, 0, stream>>>(
            xc, xn, XcatT + l * 32,
            fragConv + (size_t)l * 12 * 64 * 8,
            fragDense + (size_t)l * 2 * 64 * 8,
            b_tanh + l * 32, b_sig + l * 32, b_dense + l * 32,
            d, Lout, S);
        float* tmp = xc; xc = xn; xn = tmp;
        Lin = Lout;
    }

    // GEMM chain, chunked x2 over time; nTile = ceil(80000/256) = 313.
    const int nTile = (CH + 255) / 256;
    for (int c = 0; c < 2; ++c) {
        const int c0 = c * CH;
        // skipTc = relu(Wcat @ XcatT^T + bsum), stored [t][oc] bf16
        gemm256<true><<<nTile * 2, 512, 0, stream>>>(
            wcat, 1440, XcatT + (size_t)c0 * 1440, 1440,
            skipTc, 512, bsum, 1440, CH, 2);
        // hTc = relu(W1 @ skipTc^T + b1), stored [t][oc] bf16
        gemm256<true><<<nTile * 2, 512, 0, stream>>>(
            wp1, 512, skipTc, 512, hTc, 512, b_post1, 512, CH, 2);
        // out[:, c0:c0+CH] = W2 @ hTc^T + b2, fp32 row-major
        gemm256<false><<<nTile, 512, 0, stream>>>(
            wp2, 512, hTc, 512, out + c0, FL, b_post2, 512, CH, 1);
    }
}

// Round 2
// 1580.120 us; speedup vs baseline: 1.2265x; 1.1263x over previous
//
#include <hip/hip_runtime.h>
#include <hip/hip_bf16.h>
#include <cstdio>

typedef unsigned short ushort_t;
typedef __bf16 bf16x8 __attribute__((ext_vector_type(8)));
typedef float f32x4 __attribute__((ext_vector_type(4)));

#define FL   160000      // final sequence length
#define L0   165110      // causal conv output length
#define NL   45
#define CH   80000       // time-chunk for the GEMM chain

__device__ __forceinline__ float tanh_fast(float x) {
    float ax = fabsf(x);
    float e  = __expf(-2.f * ax);
    float r  = (1.f - e) / (1.f + e);
    return copysignf(r, x);
}
__device__ __forceinline__ float sigmoid_fast(float x) {
    return 1.f / (1.f + __expf(-x));
}

#define GLOAD_LDS16(gp, lp) \
    __builtin_amdgcn_global_load_lds( \
        (const __attribute__((address_space(1))) void*)(gp), \
        (__attribute__((address_space(3))) void*)(lp), 16, 0, 0)

// ---------------------------------------------------------------------------
// Causal conv: y[t][oc] = b[oc] + sum_k w[oc][k] * x[t+k],  t < L0
// Output layout: fp32 [t][32] rows.
// ---------------------------------------------------------------------------
__global__ __launch_bounds__(256) void causal_kernel(
    const float* __restrict__ x, const float* __restrict__ wc,
    const float* __restrict__ bc, float* __restrict__ y)
{
    __shared__ float ws_[33 * 32];
    __shared__ float bs_[32];
    const int tid = threadIdx.x;
    for (int idx = tid; idx < 33 * 32; idx += 256) {
        int k = idx >> 5, oc = idx & 31;
        ws_[idx] = wc[oc * 33 + k];             // [k][oc]
    }
    if (tid < 32) bs_[tid] = bc[tid];
    __syncthreads();
    const int t = blockIdx.x * 256 + tid;
    if (t >= L0) return;
    float acc[32];
#pragma unroll
    for (int oc = 0; oc < 32; ++oc) acc[oc] = bs_[oc];
    for (int k = 0; k < 33; ++k) {
        float xv = x[t + k];
        const float* wp = &ws_[k * 32];
#pragma unroll
        for (int oc = 0; oc < 32; ++oc) acc[oc] += wp[oc] * xv;
    }
    float* yr = y + (size_t)t * 32;
#pragma unroll
    for (int oc = 0; oc < 32; oc += 4)
        *(float4*)(yr + oc) = make_float4(acc[oc], acc[oc+1], acc[oc+2], acc[oc+3]);
}

// ---------------------------------------------------------------------------
// Prepack conv (tanh+sig stacked, M=64, K=96=(tap,ic)) and dense (M=32,K=32)
// weights into MFMA A-fragment layout: frag[slot][lane][8],
// A[m = slot_m*16 + (lane&15)][k = (lane>>4)*8 + jj].
// ---------------------------------------------------------------------------
__global__ __launch_bounds__(256) void prepack_frag(
    const float* __restrict__ wt, const float* __restrict__ wsg,
    const float* __restrict__ wd,
    __bf16* __restrict__ fragConv, __bf16* __restrict__ fragDense)
{
    const int idx = blockIdx.x * 256 + threadIdx.x;
    if (idx < NL * 12 * 64) {
        const int lane = idx & 63;
        const int rem  = idx >> 6;
        const int slot = rem % 12, l = rem / 12;
        const int j = slot >> 2, i = slot & 3;        // tap, m-tile
        const int m = (i & 1) * 16 + (lane & 15);     // row within 32
        const int quad = lane >> 4;
        const float* wsrc = (i < 2) ? wt : wsg;
        __bf16 v[8];
#pragma unroll
        for (int jj = 0; jj < 8; ++jj) {
            int ic = quad * 8 + jj;
            v[jj] = (__bf16)wsrc[((size_t)(l * 32 + m) * 32 + ic) * 3 + j];
        }
        *(uint4*)(fragConv + (size_t)idx * 8) = *(const uint4*)v;
    }
    if (idx < NL * 2 * 64) {
        const int lane = idx & 63;
        const int rem  = idx >> 6;
        const int i = rem & 1, l = rem >> 1;
        const int m = i * 16 + (lane & 15);
        const int quad = lane >> 4;
        __bf16 v[8];
#pragma unroll
        for (int jj = 0; jj < 8; ++jj)
            v[jj] = (__bf16)wd[(size_t)(l * 32 + m) * 32 + quad * 8 + jj];
        *(uint4*)(fragDense + (size_t)idx * 8) = *(const uint4*)v;
    }
}

// ---------------------------------------------------------------------------
// Fully-fused MFMA layer: conv(tanh|sig) -> gate -> skip slab (bf16) +
// dense + residual (fp32). x layout [t][32] fp32. Wave-private LDS slab,
// no __syncthreads. Each wave owns 32 t's; block = 128 t's.
// Skip slab now K-major: xslot = XcatT2 + l*FL*32, row stride 32 (coalesced).
// ---------------------------------------------------------------------------
__global__ __launch_bounds__(256) void layer_mfma(
    const float* __restrict__ xin,   // [Lin][32] fp32, Lin = Lout + 2d
    float* __restrict__ xout,        // [Lout][32] fp32
    __bf16* __restrict__ xslot,      // XcatT2 + l*FL*32, row stride 32
    const __bf16* __restrict__ fragConv,   // layer's 12*64*8
    const __bf16* __restrict__ fragDense,  // layer's 2*64*8
    const float* __restrict__ bt, const float* __restrict__ bs,
    const float* __restrict__ bd,
    int d, int Lout, int S)
{
    __shared__ __bf16 gbuf[4][32][40];   // per-wave slab, ic padded 32->40
    const int tid  = threadIdx.x;
    const int wave = tid >> 6, lane = tid & 63;
    const int fm = lane & 15, quad = lane >> 4;
    const int t0 = blockIdx.x * 128 + wave * 32;

    // A fragments (uniform across waves, L1-hot)
    bf16x8 Ac[3][4], Ad[2];
#pragma unroll
    for (int j = 0; j < 3; ++j)
#pragma unroll
        for (int i = 0; i < 4; ++i)
            Ac[j][i] = *(const bf16x8*)(fragConv + ((j * 4 + i) * 64 + lane) * 8);
#pragma unroll
    for (int i = 0; i < 2; ++i)
        Ad[i] = *(const bf16x8*)(fragDense + (i * 64 + lane) * 8);

    // conv accumulators init with biases: m-tiles 0,1 = tanh rows, 2,3 = sig
    f32x4 acc[4][2];
#pragma unroll
    for (int i = 0; i < 4; ++i) {
        const float* bb = (i < 2) ? (bt + i * 16) : (bs + (i - 2) * 16);
        float4 b4 = *(const float4*)(bb + quad * 4);
        f32x4 bi; bi[0] = b4.x; bi[1] = b4.y; bi[2] = b4.z; bi[3] = b4.w;
        acc[i][0] = bi; acc[i][1] = bi;
    }

    // conv MFMAs: B built on the fly from fp32 x rows
#pragma unroll
    for (int j2 = 0; j2 < 2; ++j2) {
        int tl = t0 + j2 * 16 + fm;
        if (tl > Lout - 1) tl = Lout - 1;
#pragma unroll
        for (int j = 0; j < 3; ++j) {
            const float* xp = xin + (size_t)(tl + j * d) * 32 + quad * 8;
            float4 u0 = *(const float4*)xp;
            float4 u1 = *(const float4*)(xp + 4);
            bf16x8 bf;
            bf[0] = (__bf16)u0.x; bf[1] = (__bf16)u0.y;
            bf[2] = (__bf16)u0.z; bf[3] = (__bf16)u0.w;
            bf[4] = (__bf16)u1.x; bf[5] = (__bf16)u1.y;
            bf[6] = (__bf16)u1.z; bf[7] = (__bf16)u1.w;
#pragma unroll
            for (int i = 0; i < 4; ++i)
                acc[i][j2] = __builtin_amdgcn_mfma_f32_16x16x32_bf16(
                    Ac[j][i], bf, acc[i][j2], 0, 0, 0);
        }
    }

    // gate: g[ic][t] = tanh(z_t) * sigmoid(z_s); write to wave slab [t][ic]
#pragma unroll
    for (int i = 0; i < 2; ++i)
#pragma unroll
        for (int j2 = 0; j2 < 2; ++j2) {
            __bf16 pk[4];
#pragma unroll
            for (int r = 0; r < 4; ++r)
                pk[r] = (__bf16)(tanh_fast(acc[i][j2][r]) *
                                 sigmoid_fast(acc[i + 2][j2][r]));
            *(uint2*)&gbuf[wave][j2 * 16 + fm][i * 16 + quad * 4] =
                *(const uint2*)pk;
        }

    // skip slab: 64 B per t row -> xslot[tw][0..32), contiguous rows
    {
        const int rr = lane >> 1, hh = lane & 1;
        const int t = t0 + rr, tw = t - S;
        if (t < Lout && (unsigned)tw < FL) {
            const char* gp = (const char*)&gbuf[wave][rr][0] + hh * 32;
            uint4 v0 = *(const uint4*)gp;
            uint4 v1 = *(const uint4*)(gp + 16);
            uint4* dst = (uint4*)(xslot + (size_t)tw * 32 + hh * 16);
            dst[0] = v0; dst[1] = v1;
        }
    }

    // dense MFMA from slab + residual + fp32 store
    f32x4 dacc[2][2];
#pragma unroll
    for (int i = 0; i < 2; ++i) {
        float4 b4 = *(const float4*)(bd + i * 16 + quad * 4);
        f32x4 bi; bi[0] = b4.x; bi[1] = b4.y; bi[2] = b4.z; bi[3] = b4.w;
        dacc[i][0] = bi; dacc[i][1] = bi;
    }
#pragma unroll
    for (int j2 = 0; j2 < 2; ++j2) {
        bf16x8 gb = *(const bf16x8*)&gbuf[wave][j2 * 16 + fm][quad * 8];
#pragma unroll
        for (int i = 0; i < 2; ++i)
            dacc[i][j2] = __builtin_amdgcn_mfma_f32_16x16x32_bf16(
                Ad[i], gb, dacc[i][j2], 0, 0, 0);
    }
#pragma unroll
    for (int i = 0; i < 2; ++i)
#pragma unroll
        for (int j2 = 0; j2 < 2; ++j2) {
            const int t = t0 + j2 * 16 + fm;
            if (t < Lout) {
                const int oc = i * 16 + quad * 4;
                float4 r4 = *(const float4*)(xin + (size_t)(t + d) * 32 + oc);
                float4 o;
                o.x = dacc[i][j2][0] + r4.x;
                o.y = dacc[i][j2][1] + r4.y;
                o.z = dacc[i][j2][2] + r4.z;
                o.w = dacc[i][j2][3] + r4.w;
                *(float4*)(xout + (size_t)t * 32 + oc) = o;
            }
        }
}

// ---------------------------------------------------------------------------
// Deep-pipelined MFMA bf16 GEMM with K-tile-strided operands:
//   element (row r, k-tile kt, k-in-tile c): base + r*ldRow + kt*kStr + c.
//   Big GEMM: A=wcat2 [l][oc][32] (ldRow=32, kStrA=512*32),
//             B=XcatT2 [l][t][32] (ldRow=32, kStrB=FL*32) -> each k-tile's
//             256-row slab is one CONTIGUOUS 16 KB block (coalesced staging).
//   Post GEMMs: row-major [r][K] (ldRow=K, kStr=32).
//   BM=256, BN=256 (clamped vs Ncur), BK=32. 8 waves, wave tile 128x64.
//   4-deep LDS ring (128 KB), staged 3 ahead, gate = vmcnt(8) + s_barrier
//   once per K-tile. 16B-chunk XOR swizzle applied to both the global
//   source address and the ds_read address (involution). XCD-bijective
//   block swizzle, m-fastest so both m-blocks of a B panel share an L2.
// ---------------------------------------------------------------------------
template<bool TSTORE>
__global__ __launch_bounds__(512, 2) void gemm256(
    const __bf16* __restrict__ A, const __bf16* __restrict__ Bt,
    void* __restrict__ Cout, int ldc,
    const float* __restrict__ bias, int K, int Ncur, int mTile,
    int ldRow, size_t kStrA, size_t kStrB)
{
    __shared__ __bf16 lds[4 * 16384];     // ring: per buf A 8192 el + B 8192 el
    const int tid  = threadIdx.x;
    const int wave = tid >> 6, lane = tid & 63;
    const int fm = lane & 15, quad = lane >> 4;
    const int wm = wave >> 2, wn = wave & 3;     // 2 x 4 wave grid

    // XCD-bijective swizzle, then m-fastest pairing
    const int nwg = gridDim.x;
    const int q8 = nwg >> 3, r8 = nwg & 7;
    const int xcd = blockIdx.x & 7, loc = blockIdx.x >> 3;
    const int sbid = (xcd < r8 ? xcd * (q8 + 1)
                               : r8 * (q8 + 1) + (xcd - r8) * q8) + loc;
    const int m0 = (sbid % mTile) * 256;
    const int n0 = (sbid / mTile) * 256;

    // ---- staging source pointers (per-lane, swizzle-compensated) ----------
    const __bf16* pS[4];
    int dstE[4];
#pragma unroll
    for (int i = 0; i < 4; ++i) {
        const int cidx = (i & 1) * 512 + tid;      // 16B-chunk index in tile
        const int r = cidx >> 2, c = cidx & 3;
        const int cs = c ^ ((r >> 1) & 3);         // inverse == forward swizzle
        if (i < 2) {
            pS[i] = A + (size_t)(m0 + r) * ldRow + cs * 8;
        } else {
            int rg = n0 + r; if (rg > Ncur - 1) rg = Ncur - 1;
            pS[i] = Bt + (size_t)rg * ldRow + cs * 8;
        }
        dstE[i] = ((i < 2) ? 0 : 8192) + (i & 1) * 4096 + wave * 512;
    }

    // ---- ds_read offsets (swizzled; s=(fm>>1)&3 invariant across frags) ---
    const int swz = ((quad ^ ((fm >> 1) & 3)) << 3);
    const int aoff = (wm * 128 + fm) * 32 + swz;
    const int boff = 8192 + (wn * 64 + fm) * 32 + swz;

    f32x4 acc[8][4] = {};

    auto do_stage = [&](int t) {
        const int pb = (t & 3) * 16384;
        const size_t ka = (size_t)t * kStrA;
        const size_t kb = (size_t)t * kStrB;
        GLOAD_LDS16(pS[0] + ka, lds + pb + dstE[0]);
        GLOAD_LDS16(pS[1] + ka, lds + pb + dstE[1]);
        GLOAD_LDS16(pS[2] + kb, lds + pb + dstE[2]);
        GLOAD_LDS16(pS[3] + kb, lds + pb + dstE[3]);
    };
    auto tile_compute = [&](int t) {
        const int pb = (t & 3) * 16384;
        bf16x8 af[8], bg[4];
#pragma unroll
        for (int i = 0; i < 8; ++i)
            af[i] = *(const bf16x8*)(lds + pb + aoff + i * 512);
#pragma unroll
        for (int j = 0; j < 4; ++j)
            bg[j] = *(const bf16x8*)(lds + pb + boff + j * 512);
        __builtin_amdgcn_s_setprio(1);
#pragma unroll
        for (int i = 0; i < 8; ++i)
#pragma unroll
            for (int j = 0; j < 4; ++j)
                acc[i][j] = __builtin_amdgcn_mfma_f32_16x16x32_bf16(
                    af[i], bg[j], acc[i][j], 0, 0, 0);
        __builtin_amdgcn_s_setprio(0);
    };

    const int NT = K >> 5;                 // K-tiles of 32 (>= 4 always here)
    do_stage(0); do_stage(1); do_stage(2);
    for (int t = 0; t < NT - 3; ++t) {
        asm volatile("s_waitcnt vmcnt(8)" ::: "memory");
        __builtin_amdgcn_s_barrier();
        __builtin_amdgcn_sched_barrier(0);
        do_stage(t + 3);
        tile_compute(t);
    }
    asm volatile("s_waitcnt vmcnt(8)" ::: "memory");
    __builtin_amdgcn_s_barrier();
    __builtin_amdgcn_sched_barrier(0);
    tile_compute(NT - 3);
    asm volatile("s_waitcnt vmcnt(4)" ::: "memory");
    __builtin_amdgcn_s_barrier();
    __builtin_amdgcn_sched_barrier(0);
    tile_compute(NT - 2);
    asm volatile("s_waitcnt vmcnt(0)" ::: "memory");
    __builtin_amdgcn_s_barrier();
    __builtin_amdgcn_sched_barrier(0);
    tile_compute(NT - 1);

    // ---- epilogue ---------------------------------------------------------
    if (TSTORE) {
        __bf16* O = (__bf16*)Cout;
#pragma unroll
        for (int i = 0; i < 8; ++i) {
            const int m = m0 + wm * 128 + i * 16 + quad * 4;
            const float4 bv = *(const float4*)(bias + m);
#pragma unroll
            for (int j = 0; j < 4; ++j) {
                const int n = n0 + wn * 64 + j * 16 + fm;
                if (n < Ncur) {
                    __bf16 pk[4];
                    pk[0] = (__bf16)fmaxf(acc[i][j][0] + bv.x, 0.f);
                    pk[1] = (__bf16)fmaxf(acc[i][j][1] + bv.y, 0.f);
                    pk[2] = (__bf16)fmaxf(acc[i][j][2] + bv.z, 0.f);
                    pk[3] = (__bf16)fmaxf(acc[i][j][3] + bv.w, 0.f);
                    *(uint2*)(O + (size_t)n * ldc + m) = *(const uint2*)pk;
                }
            }
        }
    } else {
        float* O = (float*)Cout;
#pragma unroll
        for (int i = 0; i < 8; ++i) {
            const int m = m0 + wm * 128 + i * 16 + quad * 4;
            const float4 bv = *(const float4*)(bias + m);
#pragma unroll
            for (int j = 0; j < 4; ++j) {
                const int n = n0 + wn * 64 + j * 16 + fm;
                if (n < Ncur) {
                    O[(size_t)(m + 0) * ldc + n] = acc[i][j][0] + bv.x;
                    O[(size_t)(m + 1) * ldc + n] = acc[i][j][1] + bv.y;
                    O[(size_t)(m + 2) * ldc + n] = acc[i][j][2] + bv.z;
                    O[(size_t)(m + 3) * ldc + n] = acc[i][j][3] + bv.w;
                }
            }
        }
    }
}

// ---------------------------------------------------------------------------
// Skip weights: wcat2[l][oc][ic] bf16 == w_skip's native order, flat cast.
// Also sum skip biases over layers.
// ---------------------------------------------------------------------------
__global__ __launch_bounds__(256) void repack_kernel(
    const float* __restrict__ wskip, const float* __restrict__ bskip,
    __bf16* __restrict__ wcat, float* __restrict__ bsum)
{
    const int idx = blockIdx.x * 256 + threadIdx.x;
    if (idx < NL * 512 * 32) wcat[idx] = (__bf16)wskip[idx];
    if (idx < 512) {
        float s = 0.f;
        for (int l = 0; l < NL; ++l) s += bskip[l * 512 + idx];
        bsum[idx] = s;
    }
}

__global__ __launch_bounds__(256) void repack_post(
    const float* __restrict__ w1, const float* __restrict__ w2,
    __bf16* __restrict__ wp1, __bf16* __restrict__ wp2)
{
    const int idx = blockIdx.x * 256 + threadIdx.x;
    if (idx < 512 * 512) wp1[idx] = (__bf16)w1[idx];
    if (idx < 256 * 512) wp2[idx] = (__bf16)w2[idx];
}

extern "C" void kernel_launch(void* const* d_in, const int* in_sizes, int n_in,
                              void* d_out, int out_size, void* d_ws, size_t ws_size,
                              hipStream_t stream)
{
    const float* x        = (const float*)d_in[0];
    const float* w_causal = (const float*)d_in[1];
    const float* b_causal = (const float*)d_in[2];
    const float* w_tanh   = (const float*)d_in[3];
    const float* b_tanh   = (const float*)d_in[4];
    const float* w_sig    = (const float*)d_in[5];
    const float* b_sig    = (const float*)d_in[6];
    const float* w_skip   = (const float*)d_in[7];
    const float* b_skip   = (const float*)d_in[8];
    const float* w_dense  = (const float*)d_in[9];
    const float* b_dense  = (const float*)d_in[10];
    const float* w_post1  = (const float*)d_in[11];
    const float* b_post1  = (const float*)d_in[12];
    const float* w_post2  = (const float*)d_in[13];
    const float* b_post2  = (const float*)d_in[14];
    float* out = (float*)d_out;

    // Workspace carve (bytes). Budget: ws_size = 655,360,000.
    //   XcatT2   bf16 [45][FL][32]: 460,800,000  [0 .. 460,800,000)
    //   skipTc   bf16 [CH][512]  :  81,920,000  [460,800,000 .. 542,720,000)
    //   hTc      bf16 [CH][512]  :  81,920,000  [542,720,000 .. 624,640,000)
    //   wcat2    bf16 45x512x32  :   1,474,560  [624,640,000 .. 626,114,560)
    //   wp1      bf16 512x512    :     524,288  [626,114,560 .. 626,638,848)
    //   wp2      bf16 256x512    :     262,144  [626,638,848 .. 626,900,992)
    //   bsum     fp32 512        :       2,048  [626,900,992 .. 626,903,040)
    //   fragConv bf16 45*12*512  :     552,960  [626,903,040 .. 627,456,000)
    //   fragDense bf16 45*2*512  :      92,160  [627,456,000 .. 627,548,160)
    //   xb0/xb1 (fp32 [L0][32], 21,135,360 each) overlay skipTc (dead at GEMM time)
    char* base = (char*)d_ws;
    __bf16* XcatT2 = (__bf16*)base;
    __bf16* skipTc = (__bf16*)(base + 460800000);
    __bf16* hTc    = (__bf16*)(base + 542720000);
    __bf16* wcat2  = (__bf16*)(base + 624640000);
    __bf16* wp1    = (__bf16*)(base + 626114560);
    __bf16* wp2    = (__bf16*)(base + 626638848);
    float*  bsum   = (float*)(base + 626900992);
    __bf16* fragConv  = (__bf16*)(base + 626903040);
    __bf16* fragDense = (__bf16*)(base + 627456000);
    float*  xb0    = (float*)(base + 460800000);
    float*  xb1    = (float*)(base + 460800000 + 21135360);
    const size_t need = 627548160;
    if (ws_size < need) {
        fprintf(stderr, "kernel_launch: ws_size %zu < needed %zu\n", ws_size, need);
        return;
    }

    repack_kernel<<<2880, 256, 0, stream>>>(w_skip, b_skip, wcat2, bsum);
    repack_post<<<1024, 256, 0, stream>>>(w_post1, w_post2, wp1, wp2);
    prepack_frag<<<(NL * 12 * 64 + 255) / 256, 256, 0, stream>>>(
        w_tanh, w_sig, w_dense, fragConv, fragDense);
    causal_kernel<<<(L0 + 255) / 256, 256, 0, stream>>>(x, w_causal, b_causal, xb0);

    int Lin = L0;
    int S   = 2555;              // sum of all dilations
    float* xc = xb0;
    float* xn = xb1;
    for (int l = 0; l < NL; ++l) {
        const int d = 1 << (l % 9);
        const int Lout = Lin - 2 * d;
        S -= d;                  // S_l = skip-window start after layer l
        layer_mfma<<<(Lout + 127) / 128, 256, 0, stream>>>(
            xc, xn, XcatT2 + (size_t)l * FL * 32,
            fragConv + (size_t)l * 12 * 64 * 8,
            fragDense + (size_t)l * 2 * 64 * 8,
            b_tanh + l * 32, b_sig + l * 32, b_dense + l * 32,
            d, Lout, S);
        float* tmp = xc; xc = xn; xn = tmp;
        Lin = Lout;
    }

    // GEMM chain, chunked x2 over time; nTile = ceil(80000/256) = 313.
    const int nTile = (CH + 255) / 256;
    for (int c = 0; c < 2; ++c) {
        const int c0 = c * CH;
        // skipTc = relu(Wcat @ Xcat^T + bsum), stored [t][oc] bf16
        gemm256<true><<<nTile * 2, 512, 0, stream>>>(
            wcat2, XcatT2 + (size_t)c0 * 32, skipTc, 512, bsum,
            1440, CH, 2, 32, (size_t)512 * 32, (size_t)FL * 32);
        // hTc = relu(W1 @ skipTc^T + b1), stored [t][oc] bf16
        gemm256<true><<<nTile * 2, 512, 0, stream>>>(
            wp1, skipTc, hTc, 512, b_post1, 512, CH, 2, 512, 32, 32);
        // out[:, c0:c0+CH] = W2 @ hTc^T + b2, fp32 row-major
        gemm256<false><<<nTile, 512, 0, stream>>>(
            wp2, hTc, out + c0, FL, b_post2, 512, CH, 1, 512, 32, 32);
    }
}

// Round 3
// 1576.427 us; speedup vs baseline: 1.2294x; 1.0023x over previous
//
#include <hip/hip_runtime.h>
#include <hip/hip_bf16.h>
#include <cstdio>

typedef unsigned short ushort_t;
typedef __bf16 bf16x8 __attribute__((ext_vector_type(8)));
typedef float f32x4 __attribute__((ext_vector_type(4)));

#define FL   160000      // final sequence length
#define L0   165110      // causal conv output length
#define NL   45
#define CH   80000       // time-chunk for the GEMM chain

__device__ __forceinline__ float tanh_fast(float x) {
    float ax = fabsf(x);
    float e  = __expf(-2.f * ax);
    float r  = (1.f - e) / (1.f + e);
    return copysignf(r, x);
}
__device__ __forceinline__ float sigmoid_fast(float x) {
    return 1.f / (1.f + __expf(-x));
}

#define GLOAD_LDS16(gp, lp) \
    __builtin_amdgcn_global_load_lds( \
        (const __attribute__((address_space(1))) void*)(gp), \
        (__attribute__((address_space(3))) void*)(lp), 16, 0, 0)

// ---------------------------------------------------------------------------
// Causal conv: y[t][oc] = b[oc] + sum_k w[oc][k] * x[t+k],  t < L0
// Output layout: fp32 [t][32] rows.
// ---------------------------------------------------------------------------
__global__ __launch_bounds__(256) void causal_kernel(
    const float* __restrict__ x, const float* __restrict__ wc,
    const float* __restrict__ bc, float* __restrict__ y)
{
    __shared__ float ws_[33 * 32];
    __shared__ float bs_[32];
    const int tid = threadIdx.x;
    for (int idx = tid; idx < 33 * 32; idx += 256) {
        int k = idx >> 5, oc = idx & 31;
        ws_[idx] = wc[oc * 33 + k];             // [k][oc]
    }
    if (tid < 32) bs_[tid] = bc[tid];
    __syncthreads();
    const int t = blockIdx.x * 256 + tid;
    if (t >= L0) return;
    float acc[32];
#pragma unroll
    for (int oc = 0; oc < 32; ++oc) acc[oc] = bs_[oc];
    for (int k = 0; k < 33; ++k) {
        float xv = x[t + k];
        const float* wp = &ws_[k * 32];
#pragma unroll
        for (int oc = 0; oc < 32; ++oc) acc[oc] += wp[oc] * xv;
    }
    float* yr = y + (size_t)t * 32;
#pragma unroll
    for (int oc = 0; oc < 32; oc += 4)
        *(float4*)(yr + oc) = make_float4(acc[oc], acc[oc+1], acc[oc+2], acc[oc+3]);
}

// ---------------------------------------------------------------------------
// Prepack conv (tanh+sig stacked, M=64, K=96=(tap,ic)) and dense (M=32,K=32)
// weights into MFMA A-fragment layout: frag[slot][lane][8],
// A[m = slot_m*16 + (lane&15)][k = (lane>>4)*8 + jj].
// ---------------------------------------------------------------------------
__global__ __launch_bounds__(256) void prepack_frag(
    const float* __restrict__ wt, const float* __restrict__ wsg,
    const float* __restrict__ wd,
    __bf16* __restrict__ fragConv, __bf16* __restrict__ fragDense)
{
    const int idx = blockIdx.x * 256 + threadIdx.x;
    if (idx < NL * 12 * 64) {
        const int lane = idx & 63;
        const int rem  = idx >> 6;
        const int slot = rem % 12, l = rem / 12;
        const int j = slot >> 2, i = slot & 3;        // tap, m-tile
        const int m = (i & 1) * 16 + (lane & 15);     // row within 32
        const int quad = lane >> 4;
        const float* wsrc = (i < 2) ? wt : wsg;
        __bf16 v[8];
#pragma unroll
        for (int jj = 0; jj < 8; ++jj) {
            int ic = quad * 8 + jj;
            v[jj] = (__bf16)wsrc[((size_t)(l * 32 + m) * 32 + ic) * 3 + j];
        }
        *(uint4*)(fragConv + (size_t)idx * 8) = *(const uint4*)v;
    }
    if (idx < NL * 2 * 64) {
        const int lane = idx & 63;
        const int rem  = idx >> 6;
        const int i = rem & 1, l = rem >> 1;
        const int m = i * 16 + (lane & 15);
        const int quad = lane >> 4;
        __bf16 v[8];
#pragma unroll
        for (int jj = 0; jj < 8; ++jj)
            v[jj] = (__bf16)wd[(size_t)(l * 32 + m) * 32 + quad * 8 + jj];
        *(uint4*)(fragDense + (size_t)idx * 8) = *(const uint4*)v;
    }
}

// ---------------------------------------------------------------------------
// Fully-fused MFMA layer: conv(tanh|sig) -> gate -> skip slab (bf16) +
// dense + residual (fp32). x layout [t][32] fp32. Wave-private LDS slab,
// no __syncthreads. Each wave owns 32 t's; block = 128 t's.
// Skip slab K-major: xslot = XcatT2 + l*FL*32, row stride 32 (coalesced).
// XCD-chunked bijective block swizzle (m204): neighboring t-blocks share an
// XCD L2 so tap-window halos / residual rows are L2-local re-reads.
// ---------------------------------------------------------------------------
__global__ __launch_bounds__(256) void layer_mfma(
    const float* __restrict__ xin,   // [Lin][32] fp32, Lin = Lout + 2d
    float* __restrict__ xout,        // [Lout][32] fp32
    __bf16* __restrict__ xslot,      // XcatT2 + l*FL*32, row stride 32
    const __bf16* __restrict__ fragConv,   // layer's 12*64*8
    const __bf16* __restrict__ fragDense,  // layer's 2*64*8
    const float* __restrict__ bt, const float* __restrict__ bs,
    const float* __restrict__ bd,
    int d, int Lout, int S)
{
    __shared__ __bf16 gbuf[4][32][40];   // per-wave slab, ic padded 32->40
    const int tid  = threadIdx.x;
    const int wave = tid >> 6, lane = tid & 63;
    const int fm = lane & 15, quad = lane >> 4;

    // XCD-chunked bijective swizzle
    const int nwg = gridDim.x;
    const int q8 = nwg >> 3, r8 = nwg & 7;
    const int xcd = blockIdx.x & 7, loc = blockIdx.x >> 3;
    const int bswz = (xcd < r8 ? xcd * (q8 + 1)
                               : r8 * (q8 + 1) + (xcd - r8) * q8) + loc;
    const int t0 = bswz * 128 + wave * 32;

    // A fragments (uniform across waves, L1-hot)
    bf16x8 Ac[3][4], Ad[2];
#pragma unroll
    for (int j = 0; j < 3; ++j)
#pragma unroll
        for (int i = 0; i < 4; ++i)
            Ac[j][i] = *(const bf16x8*)(fragConv + ((j * 4 + i) * 64 + lane) * 8);
#pragma unroll
    for (int i = 0; i < 2; ++i)
        Ad[i] = *(const bf16x8*)(fragDense + (i * 64 + lane) * 8);

    // conv accumulators init with biases: m-tiles 0,1 = tanh rows, 2,3 = sig
    f32x4 acc[4][2];
#pragma unroll
    for (int i = 0; i < 4; ++i) {
        const float* bb = (i < 2) ? (bt + i * 16) : (bs + (i - 2) * 16);
        float4 b4 = *(const float4*)(bb + quad * 4);
        f32x4 bi; bi[0] = b4.x; bi[1] = b4.y; bi[2] = b4.z; bi[3] = b4.w;
        acc[i][0] = bi; acc[i][1] = bi;
    }

    // conv MFMAs: B built on the fly from fp32 x rows
#pragma unroll
    for (int j2 = 0; j2 < 2; ++j2) {
        int tl = t0 + j2 * 16 + fm;
        if (tl > Lout - 1) tl = Lout - 1;
#pragma unroll
        for (int j = 0; j < 3; ++j) {
            const float* xp = xin + (size_t)(tl + j * d) * 32 + quad * 8;
            float4 u0 = *(const float4*)xp;
            float4 u1 = *(const float4*)(xp + 4);
            bf16x8 bf;
            bf[0] = (__bf16)u0.x; bf[1] = (__bf16)u0.y;
            bf[2] = (__bf16)u0.z; bf[3] = (__bf16)u0.w;
            bf[4] = (__bf16)u1.x; bf[5] = (__bf16)u1.y;
            bf[6] = (__bf16)u1.z; bf[7] = (__bf16)u1.w;
#pragma unroll
            for (int i = 0; i < 4; ++i)
                acc[i][j2] = __builtin_amdgcn_mfma_f32_16x16x32_bf16(
                    Ac[j][i], bf, acc[i][j2], 0, 0, 0);
        }
    }

    // gate: g[ic][t] = tanh(z_t) * sigmoid(z_s); write to wave slab [t][ic]
#pragma unroll
    for (int i = 0; i < 2; ++i)
#pragma unroll
        for (int j2 = 0; j2 < 2; ++j2) {
            __bf16 pk[4];
#pragma unroll
            for (int r = 0; r < 4; ++r)
                pk[r] = (__bf16)(tanh_fast(acc[i][j2][r]) *
                                 sigmoid_fast(acc[i + 2][j2][r]));
            *(uint2*)&gbuf[wave][j2 * 16 + fm][i * 16 + quad * 4] =
                *(const uint2*)pk;
        }

    // skip slab: 64 B per t row -> xslot[tw][0..32), contiguous rows
    {
        const int rr = lane >> 1, hh = lane & 1;
        const int t = t0 + rr, tw = t - S;
        if (t < Lout && (unsigned)tw < FL) {
            const char* gp = (const char*)&gbuf[wave][rr][0] + hh * 32;
            uint4 v0 = *(const uint4*)gp;
            uint4 v1 = *(const uint4*)(gp + 16);
            uint4* dst = (uint4*)(xslot + (size_t)tw * 32 + hh * 16);
            dst[0] = v0; dst[1] = v1;
        }
    }

    // dense MFMA from slab + residual + fp32 store
    f32x4 dacc[2][2];
#pragma unroll
    for (int i = 0; i < 2; ++i) {
        float4 b4 = *(const float4*)(bd + i * 16 + quad * 4);
        f32x4 bi; bi[0] = b4.x; bi[1] = b4.y; bi[2] = b4.z; bi[3] = b4.w;
        dacc[i][0] = bi; dacc[i][1] = bi;
    }
#pragma unroll
    for (int j2 = 0; j2 < 2; ++j2) {
        bf16x8 gb = *(const bf16x8*)&gbuf[wave][j2 * 16 + fm][quad * 8];
#pragma unroll
        for (int i = 0; i < 2; ++i)
            dacc[i][j2] = __builtin_amdgcn_mfma_f32_16x16x32_bf16(
                Ad[i], gb, dacc[i][j2], 0, 0, 0);
    }
#pragma unroll
    for (int i = 0; i < 2; ++i)
#pragma unroll
        for (int j2 = 0; j2 < 2; ++j2) {
            const int t = t0 + j2 * 16 + fm;
            if (t < Lout) {
                const int oc = i * 16 + quad * 4;
                float4 r4 = *(const float4*)(xin + (size_t)(t + d) * 32 + oc);
                float4 o;
                o.x = dacc[i][j2][0] + r4.x;
                o.y = dacc[i][j2][1] + r4.y;
                o.z = dacc[i][j2][2] + r4.z;
                o.w = dacc[i][j2][3] + r4.w;
                *(float4*)(xout + (size_t)t * 32 + oc) = o;
            }
        }
}

// ---------------------------------------------------------------------------
// Deep-pipelined MFMA bf16 GEMM with K-tile-strided operands, 2-phase
// per-K-tile schedule (m201/m218 pattern):
//   per 32-K tile: phase A {ds_read af[0..3]+bg[0..3], stage-issue 2 A-loads
//   of t+3, barrier, lgkmcnt(0), setprio(1)+16 MFMA, barrier}; phase B
//   {ds_read af[4..7], stage-issue 2 B-loads of t+3, barrier, lgkmcnt(0),
//   setprio(1)+16 MFMA}; then counted gate vmcnt(8)+barrier ONCE per tile
//   (loads of t+2,t+3 stay in flight across barriers). Epilogue drains
//   8 -> 4 -> 0. 4-deep LDS ring (128 KB), global_load_lds(16B) staging.
//   16B-chunk XOR swizzle applied to both the global source address and the
//   ds_read address (involution); conflict-free (PMC=0). XCD-bijective
//   block swizzle, m-fastest so both m-blocks of a B panel share an L2.
// ---------------------------------------------------------------------------
template<bool TSTORE>
__global__ __launch_bounds__(512, 2) void gemm256(
    const __bf16* __restrict__ A, const __bf16* __restrict__ Bt,
    void* __restrict__ Cout, int ldc,
    const float* __restrict__ bias, int K, int Ncur, int mTile,
    int ldRow, size_t kStrA, size_t kStrB)
{
    __shared__ __bf16 lds[4 * 16384];     // ring: per buf A 8192 el + B 8192 el
    const int tid  = threadIdx.x;
    const int wave = tid >> 6, lane = tid & 63;
    const int fm = lane & 15, quad = lane >> 4;
    const int wm = wave >> 2, wn = wave & 3;     // 2 x 4 wave grid

    // XCD-bijective swizzle, then m-fastest pairing
    const int nwg = gridDim.x;
    const int q8 = nwg >> 3, r8 = nwg & 7;
    const int xcd = blockIdx.x & 7, loc = blockIdx.x >> 3;
    const int sbid = (xcd < r8 ? xcd * (q8 + 1)
                               : r8 * (q8 + 1) + (xcd - r8) * q8) + loc;
    const int m0 = (sbid % mTile) * 256;
    const int n0 = (sbid / mTile) * 256;

    // ---- staging source pointers (per-lane, swizzle-compensated) ----------
    const __bf16* pS[4];
    int dstE[4];
#pragma unroll
    for (int i = 0; i < 4; ++i) {
        const int cidx = (i & 1) * 512 + tid;      // 16B-chunk index in tile
        const int r = cidx >> 2, c = cidx & 3;
        const int cs = c ^ ((r >> 1) & 3);         // inverse == forward swizzle
        if (i < 2) {
            pS[i] = A + (size_t)(m0 + r) * ldRow + cs * 8;
        } else {
            int rg = n0 + r; if (rg > Ncur - 1) rg = Ncur - 1;
            pS[i] = Bt + (size_t)rg * ldRow + cs * 8;
        }
        dstE[i] = ((i < 2) ? 0 : 8192) + (i & 1) * 4096 + wave * 512;
    }

    // ---- ds_read offsets (swizzled; s=(fm>>1)&3 invariant across frags) ---
    const int swz = ((quad ^ ((fm >> 1) & 3)) << 3);
    const int aoff = (wm * 128 + fm) * 32 + swz;
    const int boff = 8192 + (wn * 64 + fm) * 32 + swz;

    f32x4 acc[8][4] = {};

    auto do_stageA = [&](int t) {
        const int pb = (t & 3) * 16384;
        const size_t ka = (size_t)t * kStrA;
        GLOAD_LDS16(pS[0] + ka, lds + pb + dstE[0]);
        GLOAD_LDS16(pS[1] + ka, lds + pb + dstE[1]);
    };
    auto do_stageB = [&](int t) {
        const int pb = (t & 3) * 16384;
        const size_t kb = (size_t)t * kStrB;
        GLOAD_LDS16(pS[2] + kb, lds + pb + dstE[2]);
        GLOAD_LDS16(pS[3] + kb, lds + pb + dstE[3]);
    };

    auto tile_body = [&](int t, bool st, int gate) {
        const int pb = (t & 3) * 16384;
        bf16x8 af[4], bg[4];
        // ---- phase A: read A-half0 + B frags, issue A-stage of t+3 -------
#pragma unroll
        for (int i = 0; i < 4; ++i)
            af[i] = *(const bf16x8*)(lds + pb + aoff + i * 512);
#pragma unroll
        for (int j = 0; j < 4; ++j)
            bg[j] = *(const bf16x8*)(lds + pb + boff + j * 512);
        if (st) do_stageA(t + 3);
        __builtin_amdgcn_s_barrier();
        asm volatile("s_waitcnt lgkmcnt(0)" ::: "memory");
        __builtin_amdgcn_sched_barrier(0);
        __builtin_amdgcn_s_setprio(1);
#pragma unroll
        for (int i = 0; i < 4; ++i)
#pragma unroll
            for (int j = 0; j < 4; ++j)
                acc[i][j] = __builtin_amdgcn_mfma_f32_16x16x32_bf16(
                    af[i], bg[j], acc[i][j], 0, 0, 0);
        __builtin_amdgcn_s_setprio(0);
        __builtin_amdgcn_s_barrier();
        // ---- phase B: read A-half1, issue B-stage of t+3 ------------------
#pragma unroll
        for (int i = 0; i < 4; ++i)
            af[i] = *(const bf16x8*)(lds + pb + aoff + (i + 4) * 512);
        if (st) do_stageB(t + 3);
        __builtin_amdgcn_s_barrier();
        asm volatile("s_waitcnt lgkmcnt(0)" ::: "memory");
        __builtin_amdgcn_sched_barrier(0);
        __builtin_amdgcn_s_setprio(1);
#pragma unroll
        for (int i = 0; i < 4; ++i)
#pragma unroll
            for (int j = 0; j < 4; ++j)
                acc[i + 4][j] = __builtin_amdgcn_mfma_f32_16x16x32_bf16(
                    af[i], bg[j], acc[i + 4][j], 0, 0, 0);
        __builtin_amdgcn_s_setprio(0);
        // ---- counted gate for next tile (never 0 in main loop) ------------
        if (gate == 8)      asm volatile("s_waitcnt vmcnt(8)" ::: "memory");
        else if (gate == 4) asm volatile("s_waitcnt vmcnt(4)" ::: "memory");
        else if (gate == 0) asm volatile("s_waitcnt vmcnt(0)" ::: "memory");
        if (gate >= 0) {
            __builtin_amdgcn_s_barrier();
            __builtin_amdgcn_sched_barrier(0);
        }
    };

    const int NT = K >> 5;                 // K-tiles of 32 (>= 4 always here)
    do_stageA(0); do_stageB(0);
    do_stageA(1); do_stageB(1);
    do_stageA(2); do_stageB(2);
    asm volatile("s_waitcnt vmcnt(8)" ::: "memory");
    __builtin_amdgcn_s_barrier();
    __builtin_amdgcn_sched_barrier(0);
    for (int t = 0; t < NT - 3; ++t) tile_body(t, true, 8);
    tile_body(NT - 3, false, 4);
    tile_body(NT - 2, false, 0);
    tile_body(NT - 1, false, -1);

    // ---- epilogue ---------------------------------------------------------
    if (TSTORE) {
        __bf16* O = (__bf16*)Cout;
#pragma unroll
        for (int i = 0; i < 8; ++i) {
            const int m = m0 + wm * 128 + i * 16 + quad * 4;
            const float4 bv = *(const float4*)(bias + m);
#pragma unroll
            for (int j = 0; j < 4; ++j) {
                const int n = n0 + wn * 64 + j * 16 + fm;
                if (n < Ncur) {
                    __bf16 pk[4];
                    pk[0] = (__bf16)fmaxf(acc[i][j][0] + bv.x, 0.f);
                    pk[1] = (__bf16)fmaxf(acc[i][j][1] + bv.y, 0.f);
                    pk[2] = (__bf16)fmaxf(acc[i][j][2] + bv.z, 0.f);
                    pk[3] = (__bf16)fmaxf(acc[i][j][3] + bv.w, 0.f);
                    *(uint2*)(O + (size_t)n * ldc + m) = *(const uint2*)pk;
                }
            }
        }
    } else {
        float* O = (float*)Cout;
#pragma unroll
        for (int i = 0; i < 8; ++i) {
            const int m = m0 + wm * 128 + i * 16 + quad * 4;
            const float4 bv = *(const float4*)(bias + m);
#pragma unroll
            for (int j = 0; j < 4; ++j) {
                const int n = n0 + wn * 64 + j * 16 + fm;
                if (n < Ncur) {
                    O[(size_t)(m + 0) * ldc + n] = acc[i][j][0] + bv.x;
                    O[(size_t)(m + 1) * ldc + n] = acc[i][j][1] + bv.y;
                    O[(size_t)(m + 2) * ldc + n] = acc[i][j][2] + bv.z;
                    O[(size_t)(m + 3) * ldc + n] = acc[i][j][3] + bv.w;
                }
            }
        }
    }
}

// ---------------------------------------------------------------------------
// Skip weights: wcat2[l][oc][ic] bf16 == w_skip's native order, flat cast.
// Also sum skip biases over layers.
// ---------------------------------------------------------------------------
__global__ __launch_bounds__(256) void repack_kernel(
    const float* __restrict__ wskip, const float* __restrict__ bskip,
    __bf16* __restrict__ wcat, float* __restrict__ bsum)
{
    const int idx = blockIdx.x * 256 + threadIdx.x;
    if (idx < NL * 512 * 32) wcat[idx] = (__bf16)wskip[idx];
    if (idx < 512) {
        float s = 0.f;
        for (int l = 0; l < NL; ++l) s += bskip[l * 512 + idx];
        bsum[idx] = s;
    }
}

__global__ __launch_bounds__(256) void repack_post(
    const float* __restrict__ w1, const float* __restrict__ w2,
    __bf16* __restrict__ wp1, __bf16* __restrict__ wp2)
{
    const int idx = blockIdx.x * 256 + threadIdx.x;
    if (idx < 512 * 512) wp1[idx] = (__bf16)w1[idx];
    if (idx < 256 * 512) wp2[idx] = (__bf16)w2[idx];
}

extern "C" void kernel_launch(void* const* d_in, const int* in_sizes, int n_in,
                              void* d_out, int out_size, void* d_ws, size_t ws_size,
                              hipStream_t stream)
{
    const float* x        = (const float*)d_in[0];
    const float* w_causal = (const float*)d_in[1];
    const float* b_causal = (const float*)d_in[2];
    const float* w_tanh   = (const float*)d_in[3];
    const float* b_tanh   = (const float*)d_in[4];
    const float* w_sig    = (const float*)d_in[5];
    const float* b_sig    = (const float*)d_in[6];
    const float* w_skip   = (const float*)d_in[7];
    const float* b_skip   = (const float*)d_in[8];
    const float* w_dense  = (const float*)d_in[9];
    const float* b_dense  = (const float*)d_in[10];
    const float* w_post1  = (const float*)d_in[11];
    const float* b_post1  = (const float*)d_in[12];
    const float* w_post2  = (const float*)d_in[13];
    const float* b_post2  = (const float*)d_in[14];
    float* out = (float*)d_out;

    // Workspace carve (bytes). Budget: ws_size = 655,360,000.
    //   XcatT2   bf16 [45][FL][32]: 460,800,000  [0 .. 460,800,000)
    //   skipTc   bf16 [CH][512]  :  81,920,000  [460,800,000 .. 542,720,000)
    //   hTc      bf16 [CH][512]  :  81,920,000  [542,720,000 .. 624,640,000)
    //   wcat2    bf16 45x512x32  :   1,474,560  [624,640,000 .. 626,114,560)
    //   wp1      bf16 512x512    :     524,288  [626,114,560 .. 626,638,848)
    //   wp2      bf16 256x512    :     262,144  [626,638,848 .. 626,900,992)
    //   bsum     fp32 512        :       2,048  [626,900,992 .. 626,903,040)
    //   fragConv bf16 45*12*512  :     552,960  [626,903,040 .. 627,456,000)
    //   fragDense bf16 45*2*512  :      92,160  [627,456,000 .. 627,548,160)
    //   xb0/xb1 (fp32 [L0][32], 21,135,360 each) overlay skipTc (dead at GEMM time)
    char* base = (char*)d_ws;
    __bf16* XcatT2 = (__bf16*)base;
    __bf16* skipTc = (__bf16*)(base + 460800000);
    __bf16* hTc    = (__bf16*)(base + 542720000);
    __bf16* wcat2  = (__bf16*)(base + 624640000);
    __bf16* wp1    = (__bf16*)(base + 626114560);
    __bf16* wp2    = (__bf16*)(base + 626638848);
    float*  bsum   = (float*)(base + 626900992);
    __bf16* fragConv  = (__bf16*)(base + 626903040);
    __bf16* fragDense = (__bf16*)(base + 627456000);
    float*  xb0    = (float*)(base + 460800000);
    float*  xb1    = (float*)(base + 460800000 + 21135360);
    const size_t need = 627548160;
    if (ws_size < need) {
        fprintf(stderr, "kernel_launch: ws_size %zu < needed %zu\n", ws_size, need);
        return;
    }

    repack_kernel<<<2880, 256, 0, stream>>>(w_skip, b_skip, wcat2, bsum);
    repack_post<<<1024, 256, 0, stream>>>(w_post1, w_post2, wp1, wp2);
    prepack_frag<<<(NL * 12 * 64 + 255) / 256, 256, 0, stream>>>(
        w_tanh, w_sig, w_dense, fragConv, fragDense);
    causal_kernel<<<(L0 + 255) / 256, 256, 0, stream>>>(x, w_causal, b_causal, xb0);

    int Lin = L0;
    int S   = 2555;              // sum of all dilations
    float* xc = xb0;
    float* xn = xb1;
    for (int l = 0; l < NL; ++l) {
        const int d = 1 << (l % 9);
        const int Lout = Lin - 2 * d;
        S -= d;                  // S_l = skip-window start after layer l
        layer_mfma<<<(Lout + 127) / 128, 256, 0, stream>>>(
            xc, xn, XcatT2 + (size_t)l * FL * 32,
            fragConv + (size_t)l * 12 * 64 * 8,
            fragDense + (size_t)l * 2 * 64 * 8,
            b_tanh + l * 32, b_sig + l * 32, b_dense + l * 32,
            d, Lout, S);
        float* tmp = xc; xc = xn; xn = tmp;
        Lin = Lout;
    }

    // GEMM chain, chunked x2 over time; nTile = ceil(80000/256) = 313.
    const int nTile = (CH + 255) / 256;
    for (int c = 0; c < 2; ++c) {
        const int c0 = c * CH;
        // skipTc = relu(Wcat @ Xcat^T + bsum), stored [t][oc] bf16
        gemm256<true><<<nTile * 2, 512, 0, stream>>>(
            wcat2, XcatT2 + (size_t)c0 * 32, skipTc, 512, bsum,
            1440, CH, 2, 32, (size_t)512 * 32, (size_t)FL * 32);
        // hTc = relu(W1 @ skipTc^T + b1), stored [t][oc] bf16
        gemm256<true><<<nTile * 2, 512, 0, stream>>>(
            wp1, skipTc, hTc, 512, b_post1, 512, CH, 2, 512, 32, 32);
        // out[:, c0:c0+CH] = W2 @ hTc^T + b2, fp32 row-major
        gemm256<false><<<nTile, 512, 0, stream>>>(
            wp2, hTc, out + c0, FL, b_post2, 512, CH, 1, 512, 32, 32);
    }
}